// Round 1
// baseline (114.794 us; speedup 1.0000x reference)
//
#include <hip/hip_runtime.h>
#include <math.h>

// Problem constants (from setup_inputs: B=64, IN=1024, output_size=1024,
// D_MODEL=64, X_KS=Y_KS=32, HIDDEN=256 -> gen_x=gen_y=32)
constexpr int B    = 64;
constexpr int IN   = 1024;
constexpr int OUTN = 1024;
constexpr int H    = 256;   // HIDDEN

#define LN10000 9.210340371976184f

__device__ __forceinline__ float fast_tanh(float x) {
    // tanh(x) = (e^{2x}-1)/(e^{2x}+1); clamp avoids inf/inf
    x = fminf(fmaxf(x, -15.0f), 15.0f);
    float e = __expf(2.0f * x);
    return __fdividef(e - 1.0f, e + 1.0f);
}

// ---------------------------------------------------------------------------
// K1: positional-encoding tables + Q + per-sample x sums.
//   blocks 0..31  : Px[p,:]  = pos_enc(p)    @ W1[0:64,:]
//   blocks 32..63 : Py[p,:]  = pos_enc(p)    @ W1[64:128,:]
//   blocks 64..95 : Pb[p,:]  = pos_enc(p)    @ Wb1[32:96,:] + bb1
//   blocks 96..159: Q[b,jx,:] = x[b, jx*32:jx*32+32] @ W1[128:160,:]; S[b]=sum(x[b,:])
// ---------------------------------------------------------------------------
__global__ void k_setup(const float* __restrict__ x,
                        const float* __restrict__ W1, const float* __restrict__ b1,
                        const float* __restrict__ Wb1, const float* __restrict__ bb1,
                        float* __restrict__ Px, float* __restrict__ Py,
                        float* __restrict__ Pb, float* __restrict__ Q,
                        float* __restrict__ S) {
    __shared__ float sm[1024];
    __shared__ float red[256];
    const int blk = blockIdx.x, tid = threadIdx.x;

    if (blk < 96) {
        const int role = blk >> 5;   // 0=Px, 1=Py, 2=Pb
        const int pos  = blk & 31;
        if (tid < 32) {
            // interleaved sinusoidal: pe[2i]=sin(pos*f_i), pe[2i+1]=cos(pos*f_i)
            float freq = expf(-(2.0f * (float)tid / 64.0f) * LN10000);
            float a = (float)pos * freq;
            sm[2 * tid]     = sinf(a);
            sm[2 * tid + 1] = cosf(a);
        }
        __syncthreads();
        const float* W;
        float* dst;
        int roff;
        float acc;
        if (role == 0)      { W = W1;  roff = 0;  dst = Px; acc = 0.0f; }
        else if (role == 1) { W = W1;  roff = 64; dst = Py; acc = 0.0f; }
        else                { W = Wb1; roff = 32; dst = Pb; acc = bb1[tid]; }
        #pragma unroll 8
        for (int d = 0; d < 64; ++d)
            acc += sm[d] * W[(roff + d) * H + tid];
        dst[pos * H + tid] = acc;
    } else {
        const int b = blk - 96;
        for (int i = tid; i < IN; i += 256) sm[i] = x[b * IN + i];
        __syncthreads();
        // S[b] = sum_i x[b,i]
        float p = sm[tid] + sm[tid + 256] + sm[tid + 512] + sm[tid + 768];
        red[tid] = p;
        __syncthreads();
        for (int s = 128; s > 0; s >>= 1) {
            if (tid < s) red[tid] += red[tid + s];
            __syncthreads();
        }
        if (tid == 0) S[b] = red[0];
        // Q[b,jx,c]: W1 rows 128..159 held in registers (column c = tid)
        float wr[32];
        #pragma unroll
        for (int k = 0; k < 32; ++k) wr[k] = W1[(128 + k) * H + tid];
        for (int jx = 0; jx < 32; ++jx) {
            float acc = 0.0f;
            #pragma unroll
            for (int k = 0; k < 32; ++k) acc += sm[jx * 32 + k] * wr[k];
            Q[(b * 32 + jx) * H + tid] = acc;
        }
    }
}

// ---------------------------------------------------------------------------
// K2: v_part[b,jy,c] = sum_jx x[b, jy*32+jx] * tanh(Px[jx,c]+Py[jy,c]+Q[b,jx,c]+b1[c])
// grid = B*32 blocks (one per (b,jy)), 256 threads (c)
// ---------------------------------------------------------------------------
__global__ void k_hyper(const float* __restrict__ x, const float* __restrict__ b1,
                        const float* __restrict__ Px, const float* __restrict__ Py,
                        const float* __restrict__ Q, float* __restrict__ Vp) {
    __shared__ float xs[32];
    const int blk = blockIdx.x, tid = threadIdx.x;
    const int b = blk >> 5, jy = blk & 31;
    if (tid < 32) xs[tid] = x[b * IN + jy * 32 + tid];
    __syncthreads();
    const float pyb = Py[jy * H + tid] + b1[tid];
    const float* qb  = Q + (b * 32) * H + tid;
    const float* pxb = Px + tid;
    float acc = 0.0f;
    #pragma unroll 8
    for (int jx = 0; jx < 32; ++jx) {
        float t = pxb[jx * H] + qb[jx * H] + pyb;
        acc += xs[jx] * fast_tanh(t);
    }
    Vp[blk * H + tid] = acc;
}

// ---------------------------------------------------------------------------
// K3: v[b,:] = sum_jy Vp[b,jy,:]; out_lin[b,o] = v[b,:]·W2[:,o] + S[b]*b2[o]
// grid = B*4 blocks (one per (b, o-block of 256)), 256 threads
// ---------------------------------------------------------------------------
__global__ void k_out(const float* __restrict__ Vp, const float* __restrict__ S,
                      const float* __restrict__ W2, const float* __restrict__ b2,
                      float* __restrict__ outl) {
    __shared__ float vsh[256];
    const int blk = blockIdx.x, tid = threadIdx.x;
    const int b = blk >> 2, ob = blk & 3;
    float vv = 0.0f;
    #pragma unroll 8
    for (int jy = 0; jy < 32; ++jy) vv += Vp[(b * 32 + jy) * H + tid];
    vsh[tid] = vv;
    __syncthreads();
    const int o = ob * 256 + tid;
    float acc = S[b] * b2[o];
    #pragma unroll 8
    for (int c = 0; c < 256; ++c) acc += vsh[c] * W2[c * OUTN + o];
    outl[b * OUTN + o] = acc;
}

// ---------------------------------------------------------------------------
// K4: bias hypernetwork + final add.
//  hb[b,t,c] = tanh(sum_k out[b,t*32+k]*Wb1[k,c] + Pb[t,c])
//  final[b,t*32+k'] = out[b,t*32+k'] + hb[b,t,:]·Wb2[:,k'] + bb2[k']
// grid = B*32 blocks (one per (b,t)), 256 threads
// ---------------------------------------------------------------------------
__global__ void k_bias(const float* __restrict__ outl, const float* __restrict__ Pb,
                       const float* __restrict__ Wb1, const float* __restrict__ Wb2,
                       const float* __restrict__ bb2, float* __restrict__ out) {
    __shared__ float os[32];
    __shared__ float hbs[256];
    __shared__ float red[256];
    const int blk = blockIdx.x, tid = threadIdx.x;
    const int b = blk >> 5, t = blk & 31;
    if (tid < 32) os[tid] = outl[b * OUTN + t * 32 + tid];
    __syncthreads();
    float a = Pb[t * H + tid];
    #pragma unroll
    for (int k = 0; k < 32; ++k) a += os[k] * Wb1[k * H + tid];
    hbs[tid] = fast_tanh(a);
    __syncthreads();
    const int kp = tid & 31, ch = tid >> 5;
    float part = 0.0f;
    #pragma unroll
    for (int j = 0; j < 32; ++j) {
        int c = ch * 32 + j;
        part += hbs[c] * Wb2[c * 32 + kp];
    }
    red[tid] = part;
    __syncthreads();
    if (tid < 32) {
        float bias = bb2[tid];
        #pragma unroll
        for (int c2 = 0; c2 < 8; ++c2) bias += red[c2 * 32 + tid];
        out[b * OUTN + t * 32 + tid] = os[tid] + bias;
    }
}

// ---------------------------------------------------------------------------
extern "C" void kernel_launch(void* const* d_in, const int* in_sizes, int n_in,
                              void* d_out, int out_size, void* d_ws, size_t ws_size,
                              hipStream_t stream) {
    const float* x   = (const float*)d_in[0];
    // d_in[1] = output_size (hardcoded 1024)
    const float* W1  = (const float*)d_in[2];
    const float* b1  = (const float*)d_in[3];
    const float* W2  = (const float*)d_in[4];
    const float* b2  = (const float*)d_in[5];
    const float* Wb1 = (const float*)d_in[6];
    const float* bb1 = (const float*)d_in[7];
    const float* Wb2 = (const float*)d_in[8];
    const float* bb2 = (const float*)d_in[9];
    float* out = (float*)d_out;

    float* ws   = (float*)d_ws;
    float* Px   = ws;                       // 32*256
    float* Py   = Px + 32 * H;              // 32*256
    float* Pb   = Py + 32 * H;              // 32*256
    float* S    = Pb + 32 * H;              // 64
    float* Q    = S + 64;                   // 64*32*256
    float* Vp   = Q + B * 32 * H;           // 64*32*256
    float* outl = Vp + B * 32 * H;          // 64*1024
    // total ~4.6 MB of ws; everything read is written earlier in the same call
    // (ws is re-poisoned to 0xAA before every launch).

    hipLaunchKernelGGL(k_setup, dim3(160), dim3(256), 0, stream,
                       x, W1, b1, Wb1, bb1, Px, Py, Pb, Q, S);
    hipLaunchKernelGGL(k_hyper, dim3(B * 32), dim3(256), 0, stream,
                       x, b1, Px, Py, Q, Vp);
    hipLaunchKernelGGL(k_out, dim3(B * 4), dim3(256), 0, stream,
                       Vp, S, W2, b2, outl);
    hipLaunchKernelGGL(k_bias, dim3(B * 32), dim3(256), 0, stream,
                       outl, Pb, Wb1, Wb2, bb2, out);
}